// Round 1
// baseline (418.482 us; speedup 1.0000x reference)
//
#include <hip/hip_runtime.h>

typedef unsigned short u16;
typedef float f32x4 __attribute__((ext_vector_type(4)));
typedef __bf16 bf16x8 __attribute__((ext_vector_type(8)));

__device__ __forceinline__ u16 f2bf(float f) {
  union { float f; unsigned u; } v; v.f = f;
  unsigned r = (v.u + 0x7fffu + ((v.u >> 16) & 1u)) >> 16;
  return (u16)r;
}
__device__ __forceinline__ float bf2f(u16 h) {
  union { unsigned u; float f; } v; v.u = ((unsigned)h) << 16; return v.f;
}

#define GLOAD16(gp, lp)                                                        \
  __builtin_amdgcn_global_load_lds(                                            \
      (const __attribute__((address_space(1))) void*)(gp),                     \
      (__attribute__((address_space(3))) void*)(lp), 16, 0, 0)

// ---------------------------------------------------------------- cast weights
__global__ __launch_bounds__(256) void cast_w_kernel(
    const float* __restrict__ wq, const float* __restrict__ wk,
    const float* __restrict__ wv, const float* __restrict__ wg,
    const float* __restrict__ wo, u16* __restrict__ wcat, u16* __restrict__ wobf)
{
  int idx = blockIdx.x * 256 + threadIdx.x;   // 320 blocks -> 81920 threads
  int e = idx * 4;                            // 4 floats each
  int row = e >> 8;
  int col = e & 255;
  const float* src = (row < 256)  ? (wq + (size_t)row * 256)
                   : (row < 512)  ? (wk + (size_t)(row - 256) * 256)
                   : (row < 768)  ? (wv + (size_t)(row - 512) * 256)
                   : (row < 1024) ? (wg + (size_t)(row - 768) * 256)
                                  : (wo + (size_t)(row - 1024) * 256);
  float4 v = *(const float4*)(src + col);
  ushort4 o;
  o.x = f2bf(v.x); o.y = f2bf(v.y); o.z = f2bf(v.z); o.w = f2bf(v.w);
  if (row < 1024) *(ushort4*)(wcat + e) = o;
  else            *(ushort4*)(wobf + (e - 262144)) = o;
}

// ---------------------------------------------------------------- LN(msa)->bf16
__global__ __launch_bounds__(256) void ln_msa_kernel(
    const float* __restrict__ x, const float* __restrict__ sc,
    const float* __restrict__ bi, u16* __restrict__ mo)
{
  const int row  = blockIdx.x * 4 + (threadIdx.x >> 6);
  const int lane = threadIdx.x & 63;
  const float4 v = *(const float4*)(x + (size_t)row * 256 + lane * 4);
  float s = v.x + v.y + v.z + v.w;
  #pragma unroll
  for (int off = 1; off < 64; off <<= 1) s += __shfl_xor(s, off);
  const float mu = s * 0.00390625f;
  const float d0 = v.x - mu, d1 = v.y - mu, d2 = v.z - mu, d3 = v.w - mu;
  float vs = d0*d0 + d1*d1 + d2*d2 + d3*d3;
  #pragma unroll
  for (int off = 1; off < 64; off <<= 1) vs += __shfl_xor(vs, off);
  const float rstd = rsqrtf(vs * 0.00390625f + 1e-5f);
  const float4 scv = *(const float4*)(sc + lane * 4);
  const float4 biv = *(const float4*)(bi + lane * 4);
  ushort4 o;
  o.x = f2bf(d0 * rstd * scv.x + biv.x);
  o.y = f2bf(d1 * rstd * scv.y + biv.y);
  o.z = f2bf(d2 * rstd * scv.z + biv.z);
  o.w = f2bf(d3 * rstd * scv.w + biv.w);
  *(ushort4*)(mo + (size_t)row * 256 + lane * 4) = o;
}

// ------------------------------------------- LN(pair) + einsum('ijc,hc->hij')
__global__ __launch_bounds__(256) void ln_pair_bias_kernel(
    const float* __restrict__ pair, const float* __restrict__ sc,
    const float* __restrict__ bi, const float* __restrict__ wb,
    float* __restrict__ biasw)
{
  __shared__ float swb[1024];
  #pragma unroll
  for (int i = 0; i < 4; ++i) swb[i * 256 + threadIdx.x] = wb[i * 256 + threadIdx.x];
  __syncthreads();
  const int ij   = blockIdx.x * 4 + (threadIdx.x >> 6);   // 0..65535
  const int lane = threadIdx.x & 63;
  const float2 v = *(const float2*)(pair + (size_t)ij * 128 + lane * 2);
  float s = v.x + v.y;
  #pragma unroll
  for (int off = 1; off < 64; off <<= 1) s += __shfl_xor(s, off);
  const float mu = s * 0.0078125f;
  const float d0 = v.x - mu, d1 = v.y - mu;
  float vs = d0*d0 + d1*d1;
  #pragma unroll
  for (int off = 1; off < 64; off <<= 1) vs += __shfl_xor(vs, off);
  const float rstd = rsqrtf(vs * 0.0078125f + 1e-5f);
  const float2 scv = *(const float2*)(sc + lane * 2);
  const float2 biv = *(const float2*)(bi + lane * 2);
  const float z0 = d0 * rstd * scv.x + biv.x;
  const float z1 = d1 * rstd * scv.y + biv.y;
  float a[8];
  #pragma unroll
  for (int hh = 0; hh < 8; ++hh)
    a[hh] = z0 * swb[hh * 128 + lane * 2] + z1 * swb[hh * 128 + lane * 2 + 1];
  #pragma unroll
  for (int off = 1; off < 64; off <<= 1) {
    #pragma unroll
    for (int hh = 0; hh < 8; ++hh) a[hh] += __shfl_xor(a[hh], off);
  }
  if (lane == 0) {
    #pragma unroll
    for (int hh = 0; hh < 8; ++hh) biasw[hh * 65536 + ij] = a[hh];
  }
}

// ------------------------------------------------------- 128x128x64 bf16 GEMM
// C = A(M x 256) * B(Ncols x 256)^T ; A,B bf16 row-major K-contiguous.
// EPI 0: qkvg epilogue (scale q, sigmoid gate) ; EPI 1: final residual epilogue
template<int EPI, int NT>
__global__ __launch_bounds__(256) void gemm_bt(
    const u16* __restrict__ A, const u16* __restrict__ B,
    u16* __restrict__ Cbf, const float* __restrict__ bgate,
    float* __restrict__ Cf, const float* __restrict__ msa,
    const u16* __restrict__ gate, const float* __restrict__ bout)
{
  __shared__ u16 sA[128 * 64];
  __shared__ u16 sB[128 * 64];
  const int tid  = threadIdx.x;
  const int lane = tid & 63, w = tid >> 6;
  const int wr = w >> 1, wc = w & 1;
  const int g = lane >> 4, r15 = lane & 15;
  const int tn = blockIdx.x % NT;
  const int tm = blockIdx.x / NT;
  const size_t brow = (size_t)tm * 128;
  const int bcol = tn * 128;

  f32x4 acc[4][4] = {};

  for (int k0 = 0; k0 < 256; k0 += 64) {
    #pragma unroll
    for (int i = 0; i < 4; ++i) {
      int c = i * 256 + tid;
      int rr = c >> 3, cc = c & 7;
      int cs = cc ^ (rr & 7);
      GLOAD16(A + (brow + rr) * 256 + k0 + cs * 8, &sA[c * 8]);
      GLOAD16(B + (size_t)(bcol + rr) * 256 + k0 + cs * 8, &sB[c * 8]);
    }
    __syncthreads();
    #pragma unroll
    for (int kk = 0; kk < 2; ++kk) {
      bf16x8 af[4], bfr[4];
      #pragma unroll
      for (int m = 0; m < 4; ++m) {
        int rr = wr * 64 + m * 16 + r15;
        int cs = (kk * 4 + g) ^ (rr & 7);
        af[m] = *(const bf16x8*)&sA[rr * 64 + cs * 8];
      }
      #pragma unroll
      for (int n = 0; n < 4; ++n) {
        int rr = wc * 64 + n * 16 + r15;
        int cs = (kk * 4 + g) ^ (rr & 7);
        bfr[n] = *(const bf16x8*)&sB[rr * 64 + cs * 8];
      }
      #pragma unroll
      for (int m = 0; m < 4; ++m) {
        #pragma unroll
        for (int n = 0; n < 4; ++n)
          acc[m][n] = __builtin_amdgcn_mfma_f32_16x16x32_bf16(af[m], bfr[n], acc[m][n], 0, 0, 0);
      }
    }
    __syncthreads();
  }

  #pragma unroll
  for (int m = 0; m < 4; ++m) {
    const int row0 = (int)brow + wr * 64 + m * 16 + g * 4;
    #pragma unroll
    for (int n = 0; n < 4; ++n) {
      const int col = bcol + wc * 64 + n * 16 + r15;
      #pragma unroll
      for (int rr = 0; rr < 4; ++rr) {
        float v = acc[m][n][rr];
        const size_t orow = (size_t)(row0 + rr);
        if (EPI == 0) {
          if (col < 256) v *= 0.17677669529663687f;                 // q / sqrt(32)
          else if (col >= 768) v = 1.0f / (1.0f + __expf(-(v + bgate[col - 768])));
          Cbf[orow * 1024 + col] = f2bf(v);
        } else {
          v += bout[col];
          float gg = bf2f(gate[orow * 1024 + col]);
          Cf[orow * 256 + col] = msa[orow * 256 + col] + gg * v;
        }
      }
    }
  }
}

// --------------------------------------------------------- attention per (b,h)
__global__ __launch_bounds__(256) void attn_kernel(
    const u16* __restrict__ qkvg, const float* __restrict__ biasw,
    u16* __restrict__ attn_out)
{
  __shared__ u16 sK[256 * 32];       // 16 KB, chunk-swizzled
  __shared__ u16 sVt[32 * 264];      // V^T, padded rows (528B stride)
  __shared__ u16 sP[4][64 * 88];     // per-wave P tile, 176B stride
  const int bh = blockIdx.x;
  const int b = bh >> 3, h = bh & 7;
  const int tid = threadIdx.x, lane = tid & 63, w = tid >> 6;
  const int g = lane >> 4, r15 = lane & 15;
  const size_t rowbase = (size_t)b * 256;

  // stage K (swizzled source so linear LDS + swizzled read match)
  #pragma unroll
  for (int i = 0; i < 4; ++i) {
    int c = i * 256 + tid;
    int rr = c >> 2, cc = c & 3;
    int cs = cc ^ (rr & 3);
    GLOAD16(qkvg + (rowbase + rr) * 1024 + 256 + h * 32 + cs * 8, &sK[c * 8]);
  }
  // stage V^T (reg transpose)
  {
    const uint4* vr4 = (const uint4*)(qkvg + (rowbase + tid) * 1024 + 512 + h * 32);
    #pragma unroll
    for (int q4 = 0; q4 < 4; ++q4) {
      uint4 vv = vr4[q4];
      unsigned uu[4] = {vv.x, vv.y, vv.z, vv.w};
      #pragma unroll
      for (int p = 0; p < 4; ++p) {
        sVt[(q4 * 8 + p * 2    ) * 264 + tid] = (u16)(uu[p] & 0xffffu);
        sVt[(q4 * 8 + p * 2 + 1) * 264 + tid] = (u16)(uu[p] >> 16);
      }
    }
  }
  // Q fragments straight from global
  bf16x8 qf[4];
  #pragma unroll
  for (int m = 0; m < 4; ++m) {
    int qrow = w * 64 + m * 16 + r15;
    qf[m] = *(const bf16x8*)(qkvg + (rowbase + qrow) * 1024 + h * 32 + g * 8);
  }
  __syncthreads();

  f32x4 oacc[4][2] = {};
  float mrun[4][4], lrun[4][4];
  #pragma unroll
  for (int m = 0; m < 4; ++m) {
    #pragma unroll
    for (int rr = 0; rr < 4; ++rr) { mrun[m][rr] = -1e30f; lrun[m][rr] = 0.f; }
  }
  const float* biasH = biasw + (size_t)h * 65536;

  for (int jb = 0; jb < 4; ++jb) {
    bf16x8 kf[4];
    #pragma unroll
    for (int n = 0; n < 4; ++n) {
      int kr = jb * 64 + n * 16 + r15;
      int cs = g ^ (kr & 3);
      kf[n] = *(const bf16x8*)&sK[kr * 32 + cs * 8];
    }
    f32x4 s[4][4];
    #pragma unroll
    for (int m = 0; m < 4; ++m) {
      #pragma unroll
      for (int n = 0; n < 4; ++n) {
        f32x4 z = {0.f, 0.f, 0.f, 0.f};
        s[m][n] = __builtin_amdgcn_mfma_f32_16x16x32_bf16(qf[m], kf[n], z, 0, 0, 0);
      }
    }
    // + pair bias
    #pragma unroll
    for (int m = 0; m < 4; ++m) {
      #pragma unroll
      for (int n = 0; n < 4; ++n) {
        #pragma unroll
        for (int rr = 0; rr < 4; ++rr)
          s[m][n][rr] += biasH[(size_t)(w * 64 + m * 16 + g * 4 + rr) * 256 + jb * 64 + n * 16 + r15];
      }
    }
    // online softmax, rows live across (n frags x 16 lanes)
    #pragma unroll
    for (int m = 0; m < 4; ++m) {
      #pragma unroll
      for (int rr = 0; rr < 4; ++rr) {
        float mx = fmaxf(fmaxf(s[m][0][rr], s[m][1][rr]), fmaxf(s[m][2][rr], s[m][3][rr]));
        mx = fmaxf(mx, __shfl_xor(mx, 1));
        mx = fmaxf(mx, __shfl_xor(mx, 2));
        mx = fmaxf(mx, __shfl_xor(mx, 4));
        mx = fmaxf(mx, __shfl_xor(mx, 8));
        const float mnew = fmaxf(mrun[m][rr], mx);
        const float corr = __expf(mrun[m][rr] - mnew);
        float ls = 0.f;
        #pragma unroll
        for (int n = 0; n < 4; ++n) {
          float p = __expf(s[m][n][rr] - mnew);
          s[m][n][rr] = p; ls += p;
        }
        ls += __shfl_xor(ls, 1); ls += __shfl_xor(ls, 2);
        ls += __shfl_xor(ls, 4); ls += __shfl_xor(ls, 8);
        lrun[m][rr] = lrun[m][rr] * corr + ls;
        mrun[m][rr] = mnew;
        oacc[m][0][rr] *= corr;
        oacc[m][1][rr] *= corr;
      }
    }
    // P -> LDS (per-wave private), re-read in A-fragment layout
    #pragma unroll
    for (int m = 0; m < 4; ++m) {
      #pragma unroll
      for (int n = 0; n < 4; ++n) {
        #pragma unroll
        for (int rr = 0; rr < 4; ++rr)
          sP[w][(m * 16 + g * 4 + rr) * 88 + n * 16 + r15] = f2bf(s[m][n][rr]);
      }
    }
    asm volatile("s_waitcnt lgkmcnt(0)" ::: "memory");
    #pragma unroll
    for (int kb = 0; kb < 2; ++kb) {
      bf16x8 pf[4], vt[2];
      #pragma unroll
      for (int m = 0; m < 4; ++m)
        pf[m] = *(const bf16x8*)&sP[w][(m * 16 + r15) * 88 + kb * 32 + g * 8];
      #pragma unroll
      for (int nd = 0; nd < 2; ++nd)
        vt[nd] = *(const bf16x8*)&sVt[(nd * 16 + r15) * 264 + jb * 64 + kb * 32 + g * 8];
      #pragma unroll
      for (int m = 0; m < 4; ++m) {
        #pragma unroll
        for (int nd = 0; nd < 2; ++nd)
          oacc[m][nd] = __builtin_amdgcn_mfma_f32_16x16x32_bf16(pf[m], vt[nd], oacc[m][nd], 0, 0, 0);
      }
    }
    asm volatile("s_waitcnt lgkmcnt(0)" ::: "memory");
  }

  #pragma unroll
  for (int m = 0; m < 4; ++m) {
    #pragma unroll
    for (int rr = 0; rr < 4; ++rr) {
      const float inv = 1.0f / lrun[m][rr];
      const size_t qrow = rowbase + w * 64 + m * 16 + g * 4 + rr;
      #pragma unroll
      for (int nd = 0; nd < 2; ++nd)
        attn_out[qrow * 256 + h * 32 + nd * 16 + r15] = f2bf(oacc[m][nd][rr] * inv);
    }
  }
}

// ------------------------------------------------------------------- launcher
extern "C" void kernel_launch(void* const* d_in, const int* in_sizes, int n_in,
                              void* d_out, int out_size, void* d_ws, size_t ws_size,
                              hipStream_t stream)
{
  (void)in_sizes; (void)n_in; (void)out_size; (void)ws_size;
  const float* msa        = (const float*)d_in[0];
  const float* pair       = (const float*)d_in[1];
  const float* ln_m_scale = (const float*)d_in[2];
  const float* ln_m_bias  = (const float*)d_in[3];
  const float* ln_z_scale = (const float*)d_in[4];
  const float* ln_z_bias  = (const float*)d_in[5];
  const float* w_q        = (const float*)d_in[6];
  const float* w_k        = (const float*)d_in[7];
  const float* w_v        = (const float*)d_in[8];
  const float* w_b        = (const float*)d_in[9];
  const float* w_out      = (const float*)d_in[10];
  const float* b_out      = (const float*)d_in[11];
  const float* w_gate     = (const float*)d_in[12];
  const float* b_gate     = (const float*)d_in[13];

  char* ws = (char*)d_ws;
  u16*   m_bf   = (u16*)(ws);                    // 32768*256 bf16   = 16 MB
  u16*   wcat   = (u16*)(ws + 16777216);         // 1024*256 bf16    = 0.5 MB
  u16*   wobf   = (u16*)(ws + 17301504);         // 256*256 bf16
  u16*   qkvg   = (u16*)(ws + 17432576);         // 32768*1024 bf16  = 64 MB
  float* biasw  = (float*)(ws + 84541440);       // 8*256*256 f32    = 2 MB
  u16*   attn_o = (u16*)(ws + 86638592);         // 32768*256 bf16   = 16 MB
  float* out = (float*)d_out;

  cast_w_kernel<<<dim3(320), dim3(256), 0, stream>>>(w_q, w_k, w_v, w_gate, w_out, wcat, wobf);
  ln_msa_kernel<<<dim3(8192), dim3(256), 0, stream>>>(msa, ln_m_scale, ln_m_bias, m_bf);
  ln_pair_bias_kernel<<<dim3(16384), dim3(256), 0, stream>>>(pair, ln_z_scale, ln_z_bias, w_b, biasw);
  gemm_bt<0, 8><<<dim3(2048), dim3(256), 0, stream>>>(m_bf, wcat, qkvg, b_gate,
                                                      nullptr, nullptr, nullptr, nullptr);
  attn_kernel<<<dim3(1024), dim3(256), 0, stream>>>(qkvg, biasw, attn_o);
  gemm_bt<1, 2><<<dim3(512), dim3(256), 0, stream>>>(attn_o, wobf, nullptr, nullptr,
                                                     out, msa, qkvg + 768, b_out);
}

// Round 2
// 222.473 us; speedup vs baseline: 1.8810x; 1.8810x over previous
//
#include <hip/hip_runtime.h>

typedef unsigned short u16;
typedef float f32x4 __attribute__((ext_vector_type(4)));
typedef __bf16 bf16x8 __attribute__((ext_vector_type(8)));

__device__ __forceinline__ u16 f2bf(float f) {
  union { float f; unsigned u; } v; v.f = f;
  unsigned r = (v.u + 0x7fffu + ((v.u >> 16) & 1u)) >> 16;
  return (u16)r;
}
__device__ __forceinline__ float bf2f(u16 h) {
  union { unsigned u; float f; } v; v.u = ((unsigned)h) << 16; return v.f;
}

#define GLOAD16(gp, lp)                                                        \
  __builtin_amdgcn_global_load_lds(                                            \
      (const __attribute__((address_space(1))) void*)(gp),                     \
      (__attribute__((address_space(3))) void*)(lp), 16, 0, 0)

#define LOG2E 1.4426950408889634f

// ---------------------------------------------------------------- cast weights
__global__ __launch_bounds__(256) void cast_w_kernel(
    const float* __restrict__ wq, const float* __restrict__ wk,
    const float* __restrict__ wv, const float* __restrict__ wg,
    const float* __restrict__ wo, u16* __restrict__ wcat, u16* __restrict__ wobf)
{
  int idx = blockIdx.x * 256 + threadIdx.x;   // 320 blocks -> 81920 threads
  int e = idx * 4;                            // 4 floats each
  int row = e >> 8;
  int col = e & 255;
  const float* src = (row < 256)  ? (wq + (size_t)row * 256)
                   : (row < 512)  ? (wk + (size_t)(row - 256) * 256)
                   : (row < 768)  ? (wv + (size_t)(row - 512) * 256)
                   : (row < 1024) ? (wg + (size_t)(row - 768) * 256)
                                  : (wo + (size_t)(row - 1024) * 256);
  float4 v = *(const float4*)(src + col);
  ushort4 o;
  o.x = f2bf(v.x); o.y = f2bf(v.y); o.z = f2bf(v.z); o.w = f2bf(v.w);
  if (row < 1024) *(ushort4*)(wcat + e) = o;
  else            *(ushort4*)(wobf + (e - 262144)) = o;
}

// ---------------------------------------------------------------- LN(msa)->bf16
__global__ __launch_bounds__(256) void ln_msa_kernel(
    const float* __restrict__ x, const float* __restrict__ sc,
    const float* __restrict__ bi, u16* __restrict__ mo)
{
  const int row  = blockIdx.x * 4 + (threadIdx.x >> 6);
  const int lane = threadIdx.x & 63;
  const float4 v = *(const float4*)(x + (size_t)row * 256 + lane * 4);
  float s = v.x + v.y + v.z + v.w;
  #pragma unroll
  for (int off = 1; off < 64; off <<= 1) s += __shfl_xor(s, off);
  const float mu = s * 0.00390625f;
  const float d0 = v.x - mu, d1 = v.y - mu, d2 = v.z - mu, d3 = v.w - mu;
  float vs = d0*d0 + d1*d1 + d2*d2 + d3*d3;
  #pragma unroll
  for (int off = 1; off < 64; off <<= 1) vs += __shfl_xor(vs, off);
  const float rstd = rsqrtf(vs * 0.00390625f + 1e-5f);
  const float4 scv = *(const float4*)(sc + lane * 4);
  const float4 biv = *(const float4*)(bi + lane * 4);
  ushort4 o;
  o.x = f2bf(d0 * rstd * scv.x + biv.x);
  o.y = f2bf(d1 * rstd * scv.y + biv.y);
  o.z = f2bf(d2 * rstd * scv.z + biv.z);
  o.w = f2bf(d3 * rstd * scv.w + biv.w);
  *(ushort4*)(mo + (size_t)row * 256 + lane * 4) = o;
}

// ------------------------------------------- LN(pair) + einsum('ijc,hc->hij')
// Writes bias TRANSPOSED and pre-scaled by log2(e): biasT[h][j(key)][i(q)]
__global__ __launch_bounds__(256) void ln_pair_bias_kernel(
    const float* __restrict__ pair, const float* __restrict__ sc,
    const float* __restrict__ bi, const float* __restrict__ wb,
    float* __restrict__ biasT)
{
  __shared__ float swb[1024];
  #pragma unroll
  for (int i = 0; i < 4; ++i) swb[i * 256 + threadIdx.x] = wb[i * 256 + threadIdx.x];
  __syncthreads();
  const int ij   = blockIdx.x * 4 + (threadIdx.x >> 6);   // 0..65535
  const int lane = threadIdx.x & 63;
  const float2 v = *(const float2*)(pair + (size_t)ij * 128 + lane * 2);
  float s = v.x + v.y;
  #pragma unroll
  for (int off = 1; off < 64; off <<= 1) s += __shfl_xor(s, off);
  const float mu = s * 0.0078125f;
  const float d0 = v.x - mu, d1 = v.y - mu;
  float vs = d0*d0 + d1*d1;
  #pragma unroll
  for (int off = 1; off < 64; off <<= 1) vs += __shfl_xor(vs, off);
  const float rstd = rsqrtf(vs * 0.0078125f + 1e-5f);
  const float2 scv = *(const float2*)(sc + lane * 2);
  const float2 biv = *(const float2*)(bi + lane * 2);
  const float z0 = d0 * rstd * scv.x + biv.x;
  const float z1 = d1 * rstd * scv.y + biv.y;
  float a[8];
  #pragma unroll
  for (int hh = 0; hh < 8; ++hh)
    a[hh] = z0 * swb[hh * 128 + lane * 2] + z1 * swb[hh * 128 + lane * 2 + 1];
  #pragma unroll
  for (int off = 1; off < 64; off <<= 1) {
    #pragma unroll
    for (int hh = 0; hh < 8; ++hh) a[hh] += __shfl_xor(a[hh], off);
  }
  if (lane == 0) {
    const int i = ij >> 8, j = ij & 255;       // bias[h][i][j] -> biasT[h][j][i]
    #pragma unroll
    for (int hh = 0; hh < 8; ++hh) biasT[hh * 65536 + j * 256 + i] = a[hh] * LOG2E;
  }
}

// ------------------------------------------------------- 128x128x64 bf16 GEMM
// C = A(M x 256) * B(Ncols x 256)^T ; A,B bf16 row-major K-contiguous.
// EPI 0: qkvg epilogue (scale q by log2e/sqrt32, sigmoid gate) ; EPI 1: residual
template<int EPI, int NT>
__global__ __launch_bounds__(256) void gemm_bt(
    const u16* __restrict__ A, const u16* __restrict__ B,
    u16* __restrict__ Cbf, const float* __restrict__ bgate,
    float* __restrict__ Cf, const float* __restrict__ msa,
    const u16* __restrict__ gate, const float* __restrict__ bout)
{
  __shared__ u16 sA[128 * 64];
  __shared__ u16 sB[128 * 64];
  const int tid  = threadIdx.x;
  const int lane = tid & 63, w = tid >> 6;
  const int wr = w >> 1, wc = w & 1;
  const int g = lane >> 4, r15 = lane & 15;
  const int tn = blockIdx.x % NT;
  const int tm = blockIdx.x / NT;
  const size_t brow = (size_t)tm * 128;
  const int bcol = tn * 128;

  f32x4 acc[4][4] = {};

  for (int k0 = 0; k0 < 256; k0 += 64) {
    #pragma unroll
    for (int i = 0; i < 4; ++i) {
      int c = i * 256 + tid;
      int rr = c >> 3, cc = c & 7;
      int cs = cc ^ (rr & 7);
      GLOAD16(A + (brow + rr) * 256 + k0 + cs * 8, &sA[c * 8]);
      GLOAD16(B + (size_t)(bcol + rr) * 256 + k0 + cs * 8, &sB[c * 8]);
    }
    __syncthreads();
    #pragma unroll
    for (int kk = 0; kk < 2; ++kk) {
      bf16x8 af[4], bfr[4];
      #pragma unroll
      for (int m = 0; m < 4; ++m) {
        int rr = wr * 64 + m * 16 + r15;
        int cs = (kk * 4 + g) ^ (rr & 7);
        af[m] = *(const bf16x8*)&sA[rr * 64 + cs * 8];
      }
      #pragma unroll
      for (int n = 0; n < 4; ++n) {
        int rr = wc * 64 + n * 16 + r15;
        int cs = (kk * 4 + g) ^ (rr & 7);
        bfr[n] = *(const bf16x8*)&sB[rr * 64 + cs * 8];
      }
      #pragma unroll
      for (int m = 0; m < 4; ++m) {
        #pragma unroll
        for (int n = 0; n < 4; ++n)
          acc[m][n] = __builtin_amdgcn_mfma_f32_16x16x32_bf16(af[m], bfr[n], acc[m][n], 0, 0, 0);
      }
    }
    __syncthreads();
  }

  #pragma unroll
  for (int m = 0; m < 4; ++m) {
    const int row0 = (int)brow + wr * 64 + m * 16 + g * 4;
    #pragma unroll
    for (int n = 0; n < 4; ++n) {
      const int col = bcol + wc * 64 + n * 16 + r15;
      #pragma unroll
      for (int rr = 0; rr < 4; ++rr) {
        float v = acc[m][n][rr];
        const size_t orow = (size_t)(row0 + rr);
        if (EPI == 0) {
          if (col < 256) v *= 0.17677669529663687f * LOG2E;   // q/sqrt(32)*log2e
          else if (col >= 768) v = 1.0f / (1.0f + __expf(-(v + bgate[col - 768])));
          Cbf[orow * 1024 + col] = f2bf(v);
        } else {
          v += bout[col];
          float gg = bf2f(gate[orow * 1024 + col]);
          Cf[orow * 256 + col] = msa[orow * 256 + col] + gg * v;
        }
      }
    }
  }
}

// --------------------------------------------------------- attention
// 2048 blocks: (b, h, qhalf). Block = 128 q rows, 4 waves x 32 q.
// No K staging (direct L2 fragment loads), no online max (exp2 direct),
// denominator reduced once at the end. Bias read as float4 from biasT.
__global__ __launch_bounds__(256) void attn_kernel(
    const u16* __restrict__ qkvg, const float* __restrict__ biasT,
    u16* __restrict__ attn_out)
{
  __shared__ u16 sVt[32 * 264];      // V^T, padded rows
  __shared__ u16 sP[4][32 * 72];     // per-wave P tile (32 q x 64 k), 144B rows
  const int blk = blockIdx.x;
  const int b = blk >> 4, h = (blk >> 1) & 7, qh = blk & 1;
  const int tid = threadIdx.x, lane = tid & 63, w = tid >> 6;
  const int g = lane >> 4, r15 = lane & 15;
  const size_t rowbase = (size_t)b * 256;
  const int qbase = qh * 128;

  // stage V^T (reg transpose), all 256 key rows
  {
    const uint4* vr4 = (const uint4*)(qkvg + (rowbase + tid) * 1024 + 512 + h * 32);
    #pragma unroll
    for (int q4 = 0; q4 < 4; ++q4) {
      uint4 vv = vr4[q4];
      unsigned uu[4] = {vv.x, vv.y, vv.z, vv.w};
      #pragma unroll
      for (int p = 0; p < 4; ++p) {
        sVt[(q4 * 8 + p * 2    ) * 264 + tid] = (u16)(uu[p] & 0xffffu);
        sVt[(q4 * 8 + p * 2 + 1) * 264 + tid] = (u16)(uu[p] >> 16);
      }
    }
  }
  // Q fragments straight from global (already scaled by log2e/sqrt(32))
  bf16x8 qf[2];
  #pragma unroll
  for (int m = 0; m < 2; ++m) {
    int qrow = qbase + w * 32 + m * 16 + r15;
    qf[m] = *(const bf16x8*)(qkvg + (rowbase + qrow) * 1024 + h * 32 + g * 8);
  }
  __syncthreads();

  f32x4 oacc[2][2] = {};
  float lrun[2][4] = {};
  const float* biasH = biasT + (size_t)h * 65536;

  // prefetch jb=0 K fragments + bias
  bf16x8 kf[4];
  f32x4 bv[2][4];
  #pragma unroll
  for (int n = 0; n < 4; ++n)
    kf[n] = *(const bf16x8*)(qkvg + (rowbase + n * 16 + r15) * 1024 + 256 + h * 32 + g * 8);
  #pragma unroll
  for (int m = 0; m < 2; ++m)
    #pragma unroll
    for (int n = 0; n < 4; ++n)
      bv[m][n] = *(const f32x4*)(biasH + (size_t)(n * 16 + r15) * 256 + qbase + w * 32 + m * 16 + g * 4);

  for (int jb = 0; jb < 4; ++jb) {
    // S = Q.K^T (+bias), S[q=m*16+g*4+rr][key=n*16+r15]
    f32x4 s[2][4];
    #pragma unroll
    for (int m = 0; m < 2; ++m) {
      #pragma unroll
      for (int n = 0; n < 4; ++n) {
        f32x4 z = {0.f, 0.f, 0.f, 0.f};
        s[m][n] = __builtin_amdgcn_mfma_f32_16x16x32_bf16(qf[m], kf[n], z, 0, 0, 0);
        s[m][n] += bv[m][n];
      }
    }
    // prefetch next jb (dead regs reused; loads overlap exp+PV below)
    if (jb < 3) {
      const int j1 = jb + 1;
      #pragma unroll
      for (int n = 0; n < 4; ++n)
        kf[n] = *(const bf16x8*)(qkvg + (rowbase + j1 * 64 + n * 16 + r15) * 1024 + 256 + h * 32 + g * 8);
      #pragma unroll
      for (int m = 0; m < 2; ++m)
        #pragma unroll
        for (int n = 0; n < 4; ++n)
          bv[m][n] = *(const f32x4*)(biasH + (size_t)(j1 * 64 + n * 16 + r15) * 256 + qbase + w * 32 + m * 16 + g * 4);
    }
    // P = exp2(S) (no max subtraction; S is O(5) so safe), accumulate denom
    #pragma unroll
    for (int m = 0; m < 2; ++m) {
      #pragma unroll
      for (int n = 0; n < 4; ++n) {
        #pragma unroll
        for (int rr = 0; rr < 4; ++rr) {
          float p = __builtin_amdgcn_exp2f(s[m][n][rr]);
          s[m][n][rr] = p;
          lrun[m][rr] += p;
        }
      }
    }
    // P -> per-wave LDS tile (C layout), re-read in A-fragment layout
    #pragma unroll
    for (int m = 0; m < 2; ++m)
      #pragma unroll
      for (int n = 0; n < 4; ++n)
        #pragma unroll
        for (int rr = 0; rr < 4; ++rr)
          sP[w][(m * 16 + g * 4 + rr) * 72 + n * 16 + r15] = f2bf(s[m][n][rr]);
    asm volatile("s_waitcnt lgkmcnt(0)" ::: "memory");
    #pragma unroll
    for (int kb = 0; kb < 2; ++kb) {
      bf16x8 pf[2], vt[2];
      #pragma unroll
      for (int m = 0; m < 2; ++m)
        pf[m] = *(const bf16x8*)&sP[w][(m * 16 + r15) * 72 + kb * 32 + g * 8];
      #pragma unroll
      for (int nd = 0; nd < 2; ++nd)
        vt[nd] = *(const bf16x8*)&sVt[(nd * 16 + r15) * 264 + jb * 64 + kb * 32 + g * 8];
      #pragma unroll
      for (int m = 0; m < 2; ++m)
        #pragma unroll
        for (int nd = 0; nd < 2; ++nd)
          oacc[m][nd] = __builtin_amdgcn_mfma_f32_16x16x32_bf16(pf[m], vt[nd], oacc[m][nd], 0, 0, 0);
    }
    asm volatile("s_waitcnt lgkmcnt(0)" ::: "memory");
  }

  // denominator: one cross-lane reduce at the end
  #pragma unroll
  for (int m = 0; m < 2; ++m) {
    #pragma unroll
    for (int rr = 0; rr < 4; ++rr) {
      float l = lrun[m][rr];
      l += __shfl_xor(l, 1); l += __shfl_xor(l, 2);
      l += __shfl_xor(l, 4); l += __shfl_xor(l, 8);
      const float inv = 1.0f / l;
      const size_t qrow = rowbase + qbase + w * 32 + m * 16 + g * 4 + rr;
      #pragma unroll
      for (int nd = 0; nd < 2; ++nd)
        attn_out[qrow * 256 + h * 32 + nd * 16 + r15] = f2bf(oacc[m][nd][rr] * inv);
    }
  }
}

// ------------------------------------------------------------------- launcher
extern "C" void kernel_launch(void* const* d_in, const int* in_sizes, int n_in,
                              void* d_out, int out_size, void* d_ws, size_t ws_size,
                              hipStream_t stream)
{
  (void)in_sizes; (void)n_in; (void)out_size; (void)ws_size;
  const float* msa        = (const float*)d_in[0];
  const float* pair       = (const float*)d_in[1];
  const float* ln_m_scale = (const float*)d_in[2];
  const float* ln_m_bias  = (const float*)d_in[3];
  const float* ln_z_scale = (const float*)d_in[4];
  const float* ln_z_bias  = (const float*)d_in[5];
  const float* w_q        = (const float*)d_in[6];
  const float* w_k        = (const float*)d_in[7];
  const float* w_v        = (const float*)d_in[8];
  const float* w_b        = (const float*)d_in[9];
  const float* w_out      = (const float*)d_in[10];
  const float* b_out      = (const float*)d_in[11];
  const float* w_gate     = (const float*)d_in[12];
  const float* b_gate     = (const float*)d_in[13];

  char* ws = (char*)d_ws;
  u16*   m_bf   = (u16*)(ws);                    // 32768*256 bf16   = 16 MB
  u16*   wcat   = (u16*)(ws + 16777216);         // 1024*256 bf16    = 0.5 MB
  u16*   wobf   = (u16*)(ws + 17301504);         // 256*256 bf16
  u16*   qkvg   = (u16*)(ws + 17432576);         // 32768*1024 bf16  = 64 MB
  float* biasT  = (float*)(ws + 84541440);       // 8*256*256 f32    = 2 MB
  u16*   attn_o = (u16*)(ws + 86638592);         // 32768*256 bf16   = 16 MB
  float* out = (float*)d_out;

  cast_w_kernel<<<dim3(320), dim3(256), 0, stream>>>(w_q, w_k, w_v, w_gate, w_out, wcat, wobf);
  ln_msa_kernel<<<dim3(8192), dim3(256), 0, stream>>>(msa, ln_m_scale, ln_m_bias, m_bf);
  ln_pair_bias_kernel<<<dim3(16384), dim3(256), 0, stream>>>(pair, ln_z_scale, ln_z_bias, w_b, biasT);
  gemm_bt<0, 8><<<dim3(2048), dim3(256), 0, stream>>>(m_bf, wcat, qkvg, b_gate,
                                                      nullptr, nullptr, nullptr, nullptr);
  attn_kernel<<<dim3(2048), dim3(256), 0, stream>>>(qkvg, biasT, attn_o);
  gemm_bt<1, 2><<<dim3(512), dim3(256), 0, stream>>>(attn_o, wobf, nullptr, nullptr,
                                                     out, msa, qkvg + 768, b_out);
}

// Round 3
// 191.889 us; speedup vs baseline: 2.1808x; 1.1594x over previous
//
#include <hip/hip_runtime.h>

typedef unsigned short u16;
typedef float f32x4 __attribute__((ext_vector_type(4)));
typedef __bf16 bf16x8 __attribute__((ext_vector_type(8)));

__device__ __forceinline__ u16 f2bf(float f) {
  union { float f; unsigned u; } v; v.f = f;
  unsigned r = (v.u + 0x7fffu + ((v.u >> 16) & 1u)) >> 16;
  return (u16)r;
}
__device__ __forceinline__ float bf2f(u16 h) {
  union { unsigned u; float f; } v; v.u = ((unsigned)h) << 16; return v.f;
}

#define GLOAD16(gp, lp)                                                        \
  __builtin_amdgcn_global_load_lds(                                            \
      (const __attribute__((address_space(1))) void*)(gp),                     \
      (__attribute__((address_space(3))) void*)(lp), 16, 0, 0)

#define LOG2E 1.4426950408889634f

// ---------------------------------------------------------------- cast weights
__global__ __launch_bounds__(256) void cast_w_kernel(
    const float* __restrict__ wq, const float* __restrict__ wk,
    const float* __restrict__ wv, const float* __restrict__ wg,
    const float* __restrict__ wo, u16* __restrict__ wcat, u16* __restrict__ wobf)
{
  int idx = blockIdx.x * 256 + threadIdx.x;   // 320 blocks -> 81920 threads
  int e = idx * 4;                            // 4 floats each
  int row = e >> 8;
  int col = e & 255;
  const float* src = (row < 256)  ? (wq + (size_t)row * 256)
                   : (row < 512)  ? (wk + (size_t)(row - 256) * 256)
                   : (row < 768)  ? (wv + (size_t)(row - 512) * 256)
                   : (row < 1024) ? (wg + (size_t)(row - 768) * 256)
                                  : (wo + (size_t)(row - 1024) * 256);
  float4 v = *(const float4*)(src + col);
  ushort4 o;
  o.x = f2bf(v.x); o.y = f2bf(v.y); o.z = f2bf(v.z); o.w = f2bf(v.w);
  if (row < 1024) *(ushort4*)(wcat + e) = o;
  else            *(ushort4*)(wobf + (e - 262144)) = o;
}

// ---------------------------------------------------------------- LN(msa)->bf16
__global__ __launch_bounds__(256) void ln_msa_kernel(
    const float* __restrict__ x, const float* __restrict__ sc,
    const float* __restrict__ bi, u16* __restrict__ mo)
{
  const int row  = blockIdx.x * 4 + (threadIdx.x >> 6);
  const int lane = threadIdx.x & 63;
  const float4 v = *(const float4*)(x + (size_t)row * 256 + lane * 4);
  float s = v.x + v.y + v.z + v.w;
  #pragma unroll
  for (int off = 1; off < 64; off <<= 1) s += __shfl_xor(s, off);
  const float mu = s * 0.00390625f;
  const float d0 = v.x - mu, d1 = v.y - mu, d2 = v.z - mu, d3 = v.w - mu;
  float vs = d0*d0 + d1*d1 + d2*d2 + d3*d3;
  #pragma unroll
  for (int off = 1; off < 64; off <<= 1) vs += __shfl_xor(vs, off);
  const float rstd = rsqrtf(vs * 0.00390625f + 1e-5f);
  const float4 scv = *(const float4*)(sc + lane * 4);
  const float4 biv = *(const float4*)(bi + lane * 4);
  ushort4 o;
  o.x = f2bf(d0 * rstd * scv.x + biv.x);
  o.y = f2bf(d1 * rstd * scv.y + biv.y);
  o.z = f2bf(d2 * rstd * scv.z + biv.z);
  o.w = f2bf(d3 * rstd * scv.w + biv.w);
  *(ushort4*)(mo + (size_t)row * 256 + lane * 4) = o;
}

// ------------------------------------------- LN(pair) + einsum('ijc,hc->hij')
// Writes bias TRANSPOSED and pre-scaled by log2(e): biasT[h][j(key)][i(q)]
__global__ __launch_bounds__(256) void ln_pair_bias_kernel(
    const float* __restrict__ pair, const float* __restrict__ sc,
    const float* __restrict__ bi, const float* __restrict__ wb,
    float* __restrict__ biasT)
{
  __shared__ float swb[1024];
  #pragma unroll
  for (int i = 0; i < 4; ++i) swb[i * 256 + threadIdx.x] = wb[i * 256 + threadIdx.x];
  __syncthreads();
  const int ij   = blockIdx.x * 4 + (threadIdx.x >> 6);   // 0..65535
  const int lane = threadIdx.x & 63;
  const float2 v = *(const float2*)(pair + (size_t)ij * 128 + lane * 2);
  float s = v.x + v.y;
  #pragma unroll
  for (int off = 1; off < 64; off <<= 1) s += __shfl_xor(s, off);
  const float mu = s * 0.0078125f;
  const float d0 = v.x - mu, d1 = v.y - mu;
  float vs = d0*d0 + d1*d1;
  #pragma unroll
  for (int off = 1; off < 64; off <<= 1) vs += __shfl_xor(vs, off);
  const float rstd = rsqrtf(vs * 0.0078125f + 1e-5f);
  const float2 scv = *(const float2*)(sc + lane * 2);
  const float2 biv = *(const float2*)(bi + lane * 2);
  const float z0 = d0 * rstd * scv.x + biv.x;
  const float z1 = d1 * rstd * scv.y + biv.y;
  float a[8];
  #pragma unroll
  for (int hh = 0; hh < 8; ++hh)
    a[hh] = z0 * swb[hh * 128 + lane * 2] + z1 * swb[hh * 128 + lane * 2 + 1];
  #pragma unroll
  for (int off = 1; off < 64; off <<= 1) {
    #pragma unroll
    for (int hh = 0; hh < 8; ++hh) a[hh] += __shfl_xor(a[hh], off);
  }
  if (lane == 0) {
    const int i = ij >> 8, j = ij & 255;       // bias[h][i][j] -> biasT[h][j][i]
    #pragma unroll
    for (int hh = 0; hh < 8; ++hh) biasT[hh * 65536 + j * 256 + i] = a[hh] * LOG2E;
  }
}

// ----------------------------------------------- B-stationary small-K GEMM
// C(M x 64*NCG) = A(M x 256) * B^T ; B staged once (64 cols x 256 K = 32 KB),
// A fragments direct global->VGPR (issued before the single barrier).
// 2 row-tiles of 128 rows per block. XCD-aware mapping: all NCG col-groups of
// a row-tile land on the same XCD so the A-tile is fetched from HBM once.
// EPI 0: qkvg epilogue (scale q by log2e/sqrt32, sigmoid gate) ; EPI 1: residual
template<int EPI, int NCG>
__global__ __launch_bounds__(256) void gemm_bstat(
    const u16* __restrict__ A, const u16* __restrict__ B,
    u16* __restrict__ Cbf, const float* __restrict__ bgate,
    float* __restrict__ Cf, const float* __restrict__ msa,
    const u16* __restrict__ gate, const float* __restrict__ bout)
{
  __shared__ u16 sB[64 * 256];   // 32 KB, XOR-swizzled within 128B groups
  const int tid = threadIdx.x, lane = tid & 63, w = tid >> 6;
  const int g = lane >> 4, r15 = lane & 15;
  const int x = blockIdx.x & 7;           // XCD
  const int j = blockIdx.x >> 3;
  const int cg = j % NCG;                 // col-group (fast-varying on an XCD)
  const int rp = x * 16 + j / NCG;        // row-pair 0..127
  const int bcol = cg * 64;

  // stage B tile; source pre-swizzled so linear LDS dest + XOR read match
  #pragma unroll
  for (int i = 0; i < 8; ++i) {
    int c = i * 256 + tid;                // chunk 0..2047 (16B each)
    int col = c >> 5, s = c & 31;
    int lc = (s & 24) | ((s ^ col) & 7);  // logical chunk stored at slot s
    GLOAD16(B + (size_t)(bcol + col) * 256 + lc * 8, &sB[c * 8]);
  }

  // hoisted epilogue constants
  float gb[4] = {0.f, 0.f, 0.f, 0.f};
  if (EPI == 0 && cg >= (NCG * 3) / 4) {
    #pragma unroll
    for (int n = 0; n < 4; ++n) gb[n] = bgate[bcol - 768 + n * 16 + r15];
  }
  float bo[4];
  if (EPI == 1) {
    #pragma unroll
    for (int n = 0; n < 4; ++n) bo[n] = bout[bcol + n * 16 + r15];
  }

  for (int rt = 0; rt < 2; ++rt) {
    const size_t brow = ((size_t)rp * 2 + rt) * 128;
    // A fragments direct from global (before barrier on rt=0: latency hides
    // under the B-stage vmcnt drain)
    bf16x8 af[2][8];
    #pragma unroll
    for (int m = 0; m < 2; ++m) {
      const size_t arow = brow + w * 32 + m * 16 + r15;
      #pragma unroll
      for (int kk = 0; kk < 8; ++kk)
        af[m][kk] = *(const bf16x8*)(A + arow * 256 + kk * 32 + g * 8);
    }
    if (rt == 0) __syncthreads();

    f32x4 acc[2][4] = {};
    #pragma unroll
    for (int kk = 0; kk < 8; ++kk) {
      bf16x8 bfr[4];
      #pragma unroll
      for (int n = 0; n < 4; ++n) {
        int col = n * 16 + r15;
        int lcq = kk * 4 + g;
        int s = (lcq & 24) | ((lcq ^ col) & 7);
        bfr[n] = *(const bf16x8*)&sB[col * 256 + s * 8];
      }
      #pragma unroll
      for (int m = 0; m < 2; ++m)
        #pragma unroll
        for (int n = 0; n < 4; ++n)
          acc[m][n] = __builtin_amdgcn_mfma_f32_16x16x32_bf16(af[m][kk], bfr[n], acc[m][n], 0, 0, 0);
    }

    // epilogue
    #pragma unroll
    for (int m = 0; m < 2; ++m) {
      const int row0 = (int)brow + w * 32 + m * 16 + g * 4;
      #pragma unroll
      for (int n = 0; n < 4; ++n) {
        const int col = bcol + n * 16 + r15;
        #pragma unroll
        for (int rr = 0; rr < 4; ++rr) {
          float v = acc[m][n][rr];
          const size_t orow = (size_t)(row0 + rr);
          if (EPI == 0) {
            if (cg < NCG / 4) v *= 0.17677669529663687f * LOG2E;  // q
            else if (cg >= (NCG * 3) / 4)                         // gate
              v = 1.0f / (1.0f + __expf(-(v + gb[n])));
            Cbf[orow * 1024 + col] = f2bf(v);
          } else {
            v += bo[n];
            float gg = bf2f(gate[orow * 1024 + col]);
            Cf[orow * 256 + col] = msa[orow * 256 + col] + gg * v;
          }
        }
      }
    }
  }
}

// --------------------------------------------------------- attention
// 2048 blocks: (b, h, qhalf). Block = 128 q rows, 4 waves x 32 q.
// No K staging (direct L2 fragment loads), no online max (exp2 direct),
// denominator reduced once at the end. Bias read as float4 from biasT.
__global__ __launch_bounds__(256) void attn_kernel(
    const u16* __restrict__ qkvg, const float* __restrict__ biasT,
    u16* __restrict__ attn_out)
{
  __shared__ u16 sVt[32 * 264];      // V^T, padded rows
  __shared__ u16 sP[4][32 * 72];     // per-wave P tile (32 q x 64 k), 144B rows
  const int blk = blockIdx.x;
  const int b = blk >> 4, h = (blk >> 1) & 7, qh = blk & 1;
  const int tid = threadIdx.x, lane = tid & 63, w = tid >> 6;
  const int g = lane >> 4, r15 = lane & 15;
  const size_t rowbase = (size_t)b * 256;
  const int qbase = qh * 128;

  // stage V^T (reg transpose), all 256 key rows
  {
    const uint4* vr4 = (const uint4*)(qkvg + (rowbase + tid) * 1024 + 512 + h * 32);
    #pragma unroll
    for (int q4 = 0; q4 < 4; ++q4) {
      uint4 vv = vr4[q4];
      unsigned uu[4] = {vv.x, vv.y, vv.z, vv.w};
      #pragma unroll
      for (int p = 0; p < 4; ++p) {
        sVt[(q4 * 8 + p * 2    ) * 264 + tid] = (u16)(uu[p] & 0xffffu);
        sVt[(q4 * 8 + p * 2 + 1) * 264 + tid] = (u16)(uu[p] >> 16);
      }
    }
  }
  // Q fragments straight from global (already scaled by log2e/sqrt(32))
  bf16x8 qf[2];
  #pragma unroll
  for (int m = 0; m < 2; ++m) {
    int qrow = qbase + w * 32 + m * 16 + r15;
    qf[m] = *(const bf16x8*)(qkvg + (rowbase + qrow) * 1024 + h * 32 + g * 8);
  }
  __syncthreads();

  f32x4 oacc[2][2] = {};
  float lrun[2][4] = {};
  const float* biasH = biasT + (size_t)h * 65536;

  // prefetch jb=0 K fragments + bias
  bf16x8 kf[4];
  f32x4 bv[2][4];
  #pragma unroll
  for (int n = 0; n < 4; ++n)
    kf[n] = *(const bf16x8*)(qkvg + (rowbase + n * 16 + r15) * 1024 + 256 + h * 32 + g * 8);
  #pragma unroll
  for (int m = 0; m < 2; ++m)
    #pragma unroll
    for (int n = 0; n < 4; ++n)
      bv[m][n] = *(const f32x4*)(biasH + (size_t)(n * 16 + r15) * 256 + qbase + w * 32 + m * 16 + g * 4);

  for (int jb = 0; jb < 4; ++jb) {
    // S = Q.K^T (+bias), S[q=m*16+g*4+rr][key=n*16+r15]
    f32x4 s[2][4];
    #pragma unroll
    for (int m = 0; m < 2; ++m) {
      #pragma unroll
      for (int n = 0; n < 4; ++n) {
        f32x4 z = {0.f, 0.f, 0.f, 0.f};
        s[m][n] = __builtin_amdgcn_mfma_f32_16x16x32_bf16(qf[m], kf[n], z, 0, 0, 0);
        s[m][n] += bv[m][n];
      }
    }
    // prefetch next jb (dead regs reused; loads overlap exp+PV below)
    if (jb < 3) {
      const int j1 = jb + 1;
      #pragma unroll
      for (int n = 0; n < 4; ++n)
        kf[n] = *(const bf16x8*)(qkvg + (rowbase + j1 * 64 + n * 16 + r15) * 1024 + 256 + h * 32 + g * 8);
      #pragma unroll
      for (int m = 0; m < 2; ++m)
        #pragma unroll
        for (int n = 0; n < 4; ++n)
          bv[m][n] = *(const f32x4*)(biasH + (size_t)(j1 * 64 + n * 16 + r15) * 256 + qbase + w * 32 + m * 16 + g * 4);
    }
    // P = exp2(S) (no max subtraction; S is O(5) so safe), accumulate denom
    #pragma unroll
    for (int m = 0; m < 2; ++m) {
      #pragma unroll
      for (int n = 0; n < 4; ++n) {
        #pragma unroll
        for (int rr = 0; rr < 4; ++rr) {
          float p = __builtin_amdgcn_exp2f(s[m][n][rr]);
          s[m][n][rr] = p;
          lrun[m][rr] += p;
        }
      }
    }
    // P -> per-wave LDS tile (C layout), re-read in A-fragment layout
    #pragma unroll
    for (int m = 0; m < 2; ++m)
      #pragma unroll
      for (int n = 0; n < 4; ++n)
        #pragma unroll
        for (int rr = 0; rr < 4; ++rr)
          sP[w][(m * 16 + g * 4 + rr) * 72 + n * 16 + r15] = f2bf(s[m][n][rr]);
    asm volatile("s_waitcnt lgkmcnt(0)" ::: "memory");
    #pragma unroll
    for (int kb = 0; kb < 2; ++kb) {
      bf16x8 pf[2], vt[2];
      #pragma unroll
      for (int m = 0; m < 2; ++m)
        pf[m] = *(const bf16x8*)&sP[w][(m * 16 + r15) * 72 + kb * 32 + g * 8];
      #pragma unroll
      for (int nd = 0; nd < 2; ++nd)
        vt[nd] = *(const bf16x8*)&sVt[(nd * 16 + r15) * 264 + jb * 64 + kb * 32 + g * 8];
      #pragma unroll
      for (int m = 0; m < 2; ++m)
        #pragma unroll
        for (int nd = 0; nd < 2; ++nd)
          oacc[m][nd] = __builtin_amdgcn_mfma_f32_16x16x32_bf16(pf[m], vt[nd], oacc[m][nd], 0, 0, 0);
    }
    asm volatile("s_waitcnt lgkmcnt(0)" ::: "memory");
  }

  // denominator: one cross-lane reduce at the end
  #pragma unroll
  for (int m = 0; m < 2; ++m) {
    #pragma unroll
    for (int rr = 0; rr < 4; ++rr) {
      float l = lrun[m][rr];
      l += __shfl_xor(l, 1); l += __shfl_xor(l, 2);
      l += __shfl_xor(l, 4); l += __shfl_xor(l, 8);
      const float inv = 1.0f / l;
      const size_t qrow = rowbase + qbase + w * 32 + m * 16 + g * 4 + rr;
      #pragma unroll
      for (int nd = 0; nd < 2; ++nd)
        attn_out[qrow * 256 + h * 32 + nd * 16 + r15] = f2bf(oacc[m][nd][rr] * inv);
    }
  }
}

// ------------------------------------------------------------------- launcher
extern "C" void kernel_launch(void* const* d_in, const int* in_sizes, int n_in,
                              void* d_out, int out_size, void* d_ws, size_t ws_size,
                              hipStream_t stream)
{
  (void)in_sizes; (void)n_in; (void)out_size; (void)ws_size;
  const float* msa        = (const float*)d_in[0];
  const float* pair       = (const float*)d_in[1];
  const float* ln_m_scale = (const float*)d_in[2];
  const float* ln_m_bias  = (const float*)d_in[3];
  const float* ln_z_scale = (const float*)d_in[4];
  const float* ln_z_bias  = (const float*)d_in[5];
  const float* w_q        = (const float*)d_in[6];
  const float* w_k        = (const float*)d_in[7];
  const float* w_v        = (const float*)d_in[8];
  const float* w_b        = (const float*)d_in[9];
  const float* w_out      = (const float*)d_in[10];
  const float* b_out      = (const float*)d_in[11];
  const float* w_gate     = (const float*)d_in[12];
  const float* b_gate     = (const float*)d_in[13];

  char* ws = (char*)d_ws;
  u16*   m_bf   = (u16*)(ws);                    // 32768*256 bf16   = 16 MB
  u16*   wcat   = (u16*)(ws + 16777216);         // 1024*256 bf16    = 0.5 MB
  u16*   wobf   = (u16*)(ws + 17301504);         // 256*256 bf16
  u16*   qkvg   = (u16*)(ws + 17432576);         // 32768*1024 bf16  = 64 MB
  float* biasT  = (float*)(ws + 84541440);       // 8*256*256 f32    = 2 MB
  u16*   attn_o = (u16*)(ws + 86638592);         // 32768*256 bf16   = 16 MB
  float* out = (float*)d_out;

  cast_w_kernel<<<dim3(320), dim3(256), 0, stream>>>(w_q, w_k, w_v, w_gate, w_out, wcat, wobf);
  ln_msa_kernel<<<dim3(8192), dim3(256), 0, stream>>>(msa, ln_m_scale, ln_m_bias, m_bf);
  ln_pair_bias_kernel<<<dim3(16384), dim3(256), 0, stream>>>(pair, ln_z_scale, ln_z_bias, w_b, biasT);
  gemm_bstat<0, 16><<<dim3(2048), dim3(256), 0, stream>>>(m_bf, wcat, qkvg, b_gate,
                                                          nullptr, nullptr, nullptr, nullptr);
  attn_kernel<<<dim3(2048), dim3(256), 0, stream>>>(qkvg, biasT, attn_o);
  gemm_bstat<1, 4><<<dim3(512), dim3(256), 0, stream>>>(attn_o, wobf, nullptr, nullptr,
                                                        out, msa, qkvg + 768, b_out);
}

// Round 4
// 189.683 us; speedup vs baseline: 2.2062x; 1.0116x over previous
//
#include <hip/hip_runtime.h>

typedef unsigned short u16;
typedef float f32x4 __attribute__((ext_vector_type(4)));
typedef __bf16 bf16x8 __attribute__((ext_vector_type(8)));

__device__ __forceinline__ u16 f2bf(float f) {
  union { float f; unsigned u; } v; v.f = f;
  unsigned r = (v.u + 0x7fffu + ((v.u >> 16) & 1u)) >> 16;
  return (u16)r;
}
__device__ __forceinline__ float bf2f(u16 h) {
  union { unsigned u; float f; } v; v.u = ((unsigned)h) << 16; return v.f;
}

#define GLOAD16(gp, lp)                                                        \
  __builtin_amdgcn_global_load_lds(                                            \
      (const __attribute__((address_space(1))) void*)(gp),                     \
      (__attribute__((address_space(3))) void*)(lp), 16, 0, 0)

#define LOG2E 1.4426950408889634f

// ---------------------------------------------------------------- cast weights
__global__ __launch_bounds__(256) void cast_w_kernel(
    const float* __restrict__ wq, const float* __restrict__ wk,
    const float* __restrict__ wv, const float* __restrict__ wg,
    const float* __restrict__ wo, u16* __restrict__ wcat, u16* __restrict__ wobf)
{
  int idx = blockIdx.x * 256 + threadIdx.x;   // 320 blocks -> 81920 threads
  int e = idx * 4;                            // 4 floats each
  int row = e >> 8;
  int col = e & 255;
  const float* src = (row < 256)  ? (wq + (size_t)row * 256)
                   : (row < 512)  ? (wk + (size_t)(row - 256) * 256)
                   : (row < 768)  ? (wv + (size_t)(row - 512) * 256)
                   : (row < 1024) ? (wg + (size_t)(row - 768) * 256)
                                  : (wo + (size_t)(row - 1024) * 256);
  float4 v = *(const float4*)(src + col);
  ushort4 o;
  o.x = f2bf(v.x); o.y = f2bf(v.y); o.z = f2bf(v.z); o.w = f2bf(v.w);
  if (row < 1024) *(ushort4*)(wcat + e) = o;
  else            *(ushort4*)(wobf + (e - 262144)) = o;
}

// ---------------------------------------------------------------- LN(msa)->bf16
__global__ __launch_bounds__(256) void ln_msa_kernel(
    const float* __restrict__ x, const float* __restrict__ sc,
    const float* __restrict__ bi, u16* __restrict__ mo)
{
  const int row  = blockIdx.x * 4 + (threadIdx.x >> 6);
  const int lane = threadIdx.x & 63;
  const float4 v = *(const float4*)(x + (size_t)row * 256 + lane * 4);
  float s = v.x + v.y + v.z + v.w;
  #pragma unroll
  for (int off = 1; off < 64; off <<= 1) s += __shfl_xor(s, off);
  const float mu = s * 0.00390625f;
  const float d0 = v.x - mu, d1 = v.y - mu, d2 = v.z - mu, d3 = v.w - mu;
  float vs = d0*d0 + d1*d1 + d2*d2 + d3*d3;
  #pragma unroll
  for (int off = 1; off < 64; off <<= 1) vs += __shfl_xor(vs, off);
  const float rstd = rsqrtf(vs * 0.00390625f + 1e-5f);
  const float4 scv = *(const float4*)(sc + lane * 4);
  const float4 biv = *(const float4*)(bi + lane * 4);
  ushort4 o;
  o.x = f2bf(d0 * rstd * scv.x + biv.x);
  o.y = f2bf(d1 * rstd * scv.y + biv.y);
  o.z = f2bf(d2 * rstd * scv.z + biv.z);
  o.w = f2bf(d3 * rstd * scv.w + biv.w);
  *(ushort4*)(mo + (size_t)row * 256 + lane * 4) = o;
}

// ------------------------------------------- LN(pair) + einsum('ijc,hc->hij')
// Writes bias TRANSPOSED, bf16, pre-scaled by log2(e): biasT[h][j(key)][i(q)]
__global__ __launch_bounds__(256) void ln_pair_bias_kernel(
    const float* __restrict__ pair, const float* __restrict__ sc,
    const float* __restrict__ bi, const float* __restrict__ wb,
    u16* __restrict__ biasT)
{
  __shared__ float swb[1024];
  #pragma unroll
  for (int i = 0; i < 4; ++i) swb[i * 256 + threadIdx.x] = wb[i * 256 + threadIdx.x];
  __syncthreads();
  const int ij   = blockIdx.x * 4 + (threadIdx.x >> 6);   // 0..65535
  const int lane = threadIdx.x & 63;
  const float2 v = *(const float2*)(pair + (size_t)ij * 128 + lane * 2);
  float s = v.x + v.y;
  #pragma unroll
  for (int off = 1; off < 64; off <<= 1) s += __shfl_xor(s, off);
  const float mu = s * 0.0078125f;
  const float d0 = v.x - mu, d1 = v.y - mu;
  float vs = d0*d0 + d1*d1;
  #pragma unroll
  for (int off = 1; off < 64; off <<= 1) vs += __shfl_xor(vs, off);
  const float rstd = rsqrtf(vs * 0.0078125f + 1e-5f);
  const float2 scv = *(const float2*)(sc + lane * 2);
  const float2 biv = *(const float2*)(bi + lane * 2);
  const float z0 = d0 * rstd * scv.x + biv.x;
  const float z1 = d1 * rstd * scv.y + biv.y;
  float a[8];
  #pragma unroll
  for (int hh = 0; hh < 8; ++hh)
    a[hh] = z0 * swb[hh * 128 + lane * 2] + z1 * swb[hh * 128 + lane * 2 + 1];
  #pragma unroll
  for (int off = 1; off < 64; off <<= 1) {
    #pragma unroll
    for (int hh = 0; hh < 8; ++hh) a[hh] += __shfl_xor(a[hh], off);
  }
  if (lane == 0) {
    const int i = ij >> 8, j = ij & 255;       // bias[h][i][j] -> biasT[h][j][i]
    #pragma unroll
    for (int hh = 0; hh < 8; ++hh) biasT[hh * 65536 + j * 256 + i] = f2bf(a[hh] * LOG2E);
  }
}

// ----------------------------------------------- B-stationary small-K GEMM
// C(M x 64*NCG) = A(M x 256) * B^T ; B staged once (64 cols x 256 K = 32 KB),
// A fragments direct global->VGPR (issued before the single barrier).
// 2 row-tiles of 128 rows per block. XCD-aware mapping: all NCG col-groups of
// a row-tile land on the same XCD so the A-tile is fetched from HBM once.
// EPI 0: qkvg epilogue (scale q by log2e/sqrt32, sigmoid gate) ; EPI 1: residual
template<int EPI, int NCG>
__global__ __launch_bounds__(256) void gemm_bstat(
    const u16* __restrict__ A, const u16* __restrict__ B,
    u16* __restrict__ Cbf, const float* __restrict__ bgate,
    float* __restrict__ Cf, const float* __restrict__ msa,
    const u16* __restrict__ gate, const float* __restrict__ bout)
{
  __shared__ u16 sB[64 * 256];   // 32 KB, XOR-swizzled within 128B groups
  const int tid = threadIdx.x, lane = tid & 63, w = tid >> 6;
  const int g = lane >> 4, r15 = lane & 15;
  const int x = blockIdx.x & 7;           // XCD
  const int j = blockIdx.x >> 3;
  const int cg = j % NCG;                 // col-group (fast-varying on an XCD)
  const int rp = x * 16 + j / NCG;        // row-pair 0..127
  const int bcol = cg * 64;

  // stage B tile; source pre-swizzled so linear LDS dest + XOR read match
  #pragma unroll
  for (int i = 0; i < 8; ++i) {
    int c = i * 256 + tid;                // chunk 0..2047 (16B each)
    int col = c >> 5, s = c & 31;
    int lc = (s & 24) | ((s ^ col) & 7);  // logical chunk stored at slot s
    GLOAD16(B + (size_t)(bcol + col) * 256 + lc * 8, &sB[c * 8]);
  }

  // hoisted epilogue constants
  float gb[4] = {0.f, 0.f, 0.f, 0.f};
  if (EPI == 0 && cg >= (NCG * 3) / 4) {
    #pragma unroll
    for (int n = 0; n < 4; ++n) gb[n] = bgate[bcol - 768 + n * 16 + r15];
  }
  float bo[4];
  if (EPI == 1) {
    #pragma unroll
    for (int n = 0; n < 4; ++n) bo[n] = bout[bcol + n * 16 + r15];
  }

  for (int rt = 0; rt < 2; ++rt) {
    const size_t brow = ((size_t)rp * 2 + rt) * 128;
    // A fragments direct from global (before barrier on rt=0: latency hides
    // under the B-stage vmcnt drain)
    bf16x8 af[2][8];
    #pragma unroll
    for (int m = 0; m < 2; ++m) {
      const size_t arow = brow + w * 32 + m * 16 + r15;
      #pragma unroll
      for (int kk = 0; kk < 8; ++kk)
        af[m][kk] = *(const bf16x8*)(A + arow * 256 + kk * 32 + g * 8);
    }
    if (rt == 0) __syncthreads();

    f32x4 acc[2][4] = {};
    #pragma unroll
    for (int kk = 0; kk < 8; ++kk) {
      bf16x8 bfr[4];
      #pragma unroll
      for (int n = 0; n < 4; ++n) {
        int col = n * 16 + r15;
        int lcq = kk * 4 + g;
        int s = (lcq & 24) | ((lcq ^ col) & 7);
        bfr[n] = *(const bf16x8*)&sB[col * 256 + s * 8];
      }
      #pragma unroll
      for (int m = 0; m < 2; ++m)
        #pragma unroll
        for (int n = 0; n < 4; ++n)
          acc[m][n] = __builtin_amdgcn_mfma_f32_16x16x32_bf16(af[m][kk], bfr[n], acc[m][n], 0, 0, 0);
    }

    // epilogue
    #pragma unroll
    for (int m = 0; m < 2; ++m) {
      const int row0 = (int)brow + w * 32 + m * 16 + g * 4;
      #pragma unroll
      for (int n = 0; n < 4; ++n) {
        const int col = bcol + n * 16 + r15;
        #pragma unroll
        for (int rr = 0; rr < 4; ++rr) {
          float v = acc[m][n][rr];
          const size_t orow = (size_t)(row0 + rr);
          if (EPI == 0) {
            if (cg < NCG / 4) v *= 0.17677669529663687f * LOG2E;  // q
            else if (cg >= (NCG * 3) / 4)                         // gate
              v = 1.0f / (1.0f + __expf(-(v + gb[n])));
            Cbf[orow * 1024 + col] = f2bf(v);
          } else {
            v += bo[n];
            float gg = bf2f(gate[orow * 1024 + col]);
            Cf[orow * 256 + col] = msa[orow * 256 + col] + gg * v;
          }
        }
      }
    }
  }
}

// --------------------------------------------------------- attention
// 2048 blocks, XCD-aware: h = blk&7 (one head per XCD -> bias/K/V L2-resident),
// qh = (blk>>3)&1 adjacent so the two q-halves of a b reuse K/V in L2.
// Block = 128 q rows, 4 waves x 32 q. K direct from L2, exp2 w/o max,
// denominator reduced once at the end. Bias bf16 (pre-scaled by log2e).
__global__ __launch_bounds__(256) void attn_kernel(
    const u16* __restrict__ qkvg, const u16* __restrict__ biasT,
    u16* __restrict__ attn_out)
{
  __shared__ u16 sVt[32 * 264];      // V^T, padded rows
  __shared__ u16 sP[4][32 * 72];     // per-wave P tile (32 q x 64 k), 144B rows
  const int blk = blockIdx.x;
  const int h = blk & 7;             // head == XCD
  const int idx = blk >> 3;
  const int qh = idx & 1;
  const int b = idx >> 1;
  const int tid = threadIdx.x, lane = tid & 63, w = tid >> 6;
  const int g = lane >> 4, r15 = lane & 15;
  const size_t rowbase = (size_t)b * 256;
  const int qbase = qh * 128;

  // stage V^T (reg transpose), all 256 key rows
  {
    const uint4* vr4 = (const uint4*)(qkvg + (rowbase + tid) * 1024 + 512 + h * 32);
    #pragma unroll
    for (int q4 = 0; q4 < 4; ++q4) {
      uint4 vv = vr4[q4];
      unsigned uu[4] = {vv.x, vv.y, vv.z, vv.w};
      #pragma unroll
      for (int p = 0; p < 4; ++p) {
        sVt[(q4 * 8 + p * 2    ) * 264 + tid] = (u16)(uu[p] & 0xffffu);
        sVt[(q4 * 8 + p * 2 + 1) * 264 + tid] = (u16)(uu[p] >> 16);
      }
    }
  }
  // Q fragments straight from global (already scaled by log2e/sqrt(32))
  bf16x8 qf[2];
  #pragma unroll
  for (int m = 0; m < 2; ++m) {
    int qrow = qbase + w * 32 + m * 16 + r15;
    qf[m] = *(const bf16x8*)(qkvg + (rowbase + qrow) * 1024 + h * 32 + g * 8);
  }
  __syncthreads();

  f32x4 oacc[2][2] = {};
  float lrun[2][4] = {};
  const u16* biasH = biasT + (size_t)h * 65536;

  // prefetch jb=0 K fragments + bias (bf16, 8B per frag)
  bf16x8 kf[4];
  ushort4 bvu[2][4];
  #pragma unroll
  for (int n = 0; n < 4; ++n)
    kf[n] = *(const bf16x8*)(qkvg + (rowbase + n * 16 + r15) * 1024 + 256 + h * 32 + g * 8);
  #pragma unroll
  for (int m = 0; m < 2; ++m)
    #pragma unroll
    for (int n = 0; n < 4; ++n)
      bvu[m][n] = *(const ushort4*)(biasH + (size_t)(n * 16 + r15) * 256 + qbase + w * 32 + m * 16 + g * 4);

  for (int jb = 0; jb < 4; ++jb) {
    // S = Q.K^T (+bias), S[q=m*16+g*4+rr][key=n*16+r15]
    f32x4 s[2][4];
    #pragma unroll
    for (int m = 0; m < 2; ++m) {
      #pragma unroll
      for (int n = 0; n < 4; ++n) {
        f32x4 z = {0.f, 0.f, 0.f, 0.f};
        s[m][n] = __builtin_amdgcn_mfma_f32_16x16x32_bf16(qf[m], kf[n], z, 0, 0, 0);
        const u16* bb = (const u16*)&bvu[m][n];
        #pragma unroll
        for (int rr = 0; rr < 4; ++rr) s[m][n][rr] += bf2f(bb[rr]);
      }
    }
    // prefetch next jb (dead regs reused; loads overlap exp+PV below)
    if (jb < 3) {
      const int j1 = jb + 1;
      #pragma unroll
      for (int n = 0; n < 4; ++n)
        kf[n] = *(const bf16x8*)(qkvg + (rowbase + j1 * 64 + n * 16 + r15) * 1024 + 256 + h * 32 + g * 8);
      #pragma unroll
      for (int m = 0; m < 2; ++m)
        #pragma unroll
        for (int n = 0; n < 4; ++n)
          bvu[m][n] = *(const ushort4*)(biasH + (size_t)(j1 * 64 + n * 16 + r15) * 256 + qbase + w * 32 + m * 16 + g * 4);
    }
    // P = exp2(S) (no max subtraction; S is O(5) so safe), accumulate denom
    #pragma unroll
    for (int m = 0; m < 2; ++m) {
      #pragma unroll
      for (int n = 0; n < 4; ++n) {
        #pragma unroll
        for (int rr = 0; rr < 4; ++rr) {
          float p = __builtin_amdgcn_exp2f(s[m][n][rr]);
          s[m][n][rr] = p;
          lrun[m][rr] += p;
        }
      }
    }
    // P -> per-wave LDS tile (C layout), re-read in A-fragment layout
    #pragma unroll
    for (int m = 0; m < 2; ++m)
      #pragma unroll
      for (int n = 0; n < 4; ++n)
        #pragma unroll
        for (int rr = 0; rr < 4; ++rr)
          sP[w][(m * 16 + g * 4 + rr) * 72 + n * 16 + r15] = f2bf(s[m][n][rr]);
    asm volatile("s_waitcnt lgkmcnt(0)" ::: "memory");
    #pragma unroll
    for (int kb = 0; kb < 2; ++kb) {
      bf16x8 pf[2], vt[2];
      #pragma unroll
      for (int m = 0; m < 2; ++m)
        pf[m] = *(const bf16x8*)&sP[w][(m * 16 + r15) * 72 + kb * 32 + g * 8];
      #pragma unroll
      for (int nd = 0; nd < 2; ++nd)
        vt[nd] = *(const bf16x8*)&sVt[(nd * 16 + r15) * 264 + jb * 64 + kb * 32 + g * 8];
      #pragma unroll
      for (int m = 0; m < 2; ++m)
        #pragma unroll
        for (int nd = 0; nd < 2; ++nd)
          oacc[m][nd] = __builtin_amdgcn_mfma_f32_16x16x32_bf16(pf[m], vt[nd], oacc[m][nd], 0, 0, 0);
    }
    asm volatile("s_waitcnt lgkmcnt(0)" ::: "memory");
  }

  // denominator: one cross-lane reduce at the end
  #pragma unroll
  for (int m = 0; m < 2; ++m) {
    #pragma unroll
    for (int rr = 0; rr < 4; ++rr) {
      float l = lrun[m][rr];
      l += __shfl_xor(l, 1); l += __shfl_xor(l, 2);
      l += __shfl_xor(l, 4); l += __shfl_xor(l, 8);
      const float inv = 1.0f / l;
      const size_t qrow = rowbase + qbase + w * 32 + m * 16 + g * 4 + rr;
      #pragma unroll
      for (int nd = 0; nd < 2; ++nd)
        attn_out[qrow * 256 + h * 32 + nd * 16 + r15] = f2bf(oacc[m][nd][rr] * inv);
    }
  }
}

// ------------------------------------------------------------------- launcher
extern "C" void kernel_launch(void* const* d_in, const int* in_sizes, int n_in,
                              void* d_out, int out_size, void* d_ws, size_t ws_size,
                              hipStream_t stream)
{
  (void)in_sizes; (void)n_in; (void)out_size; (void)ws_size;
  const float* msa        = (const float*)d_in[0];
  const float* pair       = (const float*)d_in[1];
  const float* ln_m_scale = (const float*)d_in[2];
  const float* ln_m_bias  = (const float*)d_in[3];
  const float* ln_z_scale = (const float*)d_in[4];
  const float* ln_z_bias  = (const float*)d_in[5];
  const float* w_q        = (const float*)d_in[6];
  const float* w_k        = (const float*)d_in[7];
  const float* w_v        = (const float*)d_in[8];
  const float* w_b        = (const float*)d_in[9];
  const float* w_out      = (const float*)d_in[10];
  const float* b_out      = (const float*)d_in[11];
  const float* w_gate     = (const float*)d_in[12];
  const float* b_gate     = (const float*)d_in[13];

  char* ws = (char*)d_ws;
  u16*   m_bf   = (u16*)(ws);                    // 32768*256 bf16   = 16 MB
  u16*   wcat   = (u16*)(ws + 16777216);         // 1024*256 bf16    = 0.5 MB
  u16*   wobf   = (u16*)(ws + 17301504);         // 256*256 bf16
  u16*   qkvg   = (u16*)(ws + 17432576);         // 32768*1024 bf16  = 64 MB
  u16*   biasT  = (u16*)(ws + 84541440);         // 8*256*256 bf16   = 1 MB
  u16*   attn_o = (u16*)(ws + 86638592);         // 32768*256 bf16   = 16 MB
  float* out = (float*)d_out;

  cast_w_kernel<<<dim3(320), dim3(256), 0, stream>>>(w_q, w_k, w_v, w_gate, w_out, wcat, wobf);
  ln_msa_kernel<<<dim3(8192), dim3(256), 0, stream>>>(msa, ln_m_scale, ln_m_bias, m_bf);
  ln_pair_bias_kernel<<<dim3(16384), dim3(256), 0, stream>>>(pair, ln_z_scale, ln_z_bias, w_b, biasT);
  gemm_bstat<0, 16><<<dim3(2048), dim3(256), 0, stream>>>(m_bf, wcat, qkvg, b_gate,
                                                          nullptr, nullptr, nullptr, nullptr);
  attn_kernel<<<dim3(2048), dim3(256), 0, stream>>>(qkvg, biasT, attn_o);
  gemm_bstat<1, 4><<<dim3(512), dim3(256), 0, stream>>>(attn_o, wobf, nullptr, nullptr,
                                                        out, msa, qkvg + 768, b_out);
}